// Round 7
// baseline (1452.934 us; speedup 1.0000x reference)
//
#include <hip/hip_runtime.h>
#include <hip/hip_bf16.h>

typedef unsigned short ushort_t;

constexpr int CB = 2, CS = 512, CD = 1024, CH = 16, CHD = 64;
constexpr int CST = 2048, CLT = 6144;
constexpr int CKST = 204, CKLT = 614;

__device__ __forceinline__ float u2f(unsigned u) { return __uint_as_float(u); }
__device__ __forceinline__ float bf2f(ushort_t u) {
  return __uint_as_float(((unsigned)u) << 16);
}
__device__ __forceinline__ ushort_t f2bf(float f) {
  __hip_bfloat16 h = __float2bfloat16(f);
  return *reinterpret_cast<ushort_t*>(&h);
}
// monotone 16-bit key: mono(a) > mono(b) <=> bf16 a > b
__device__ __forceinline__ int mono16(ushort_t u) {
  return (u & 0x8000) ? (int)((ushort_t)~u) : (int)(u | 0x8000);
}

__device__ __forceinline__ float block_sum_f(float v, float* scratch, int tid) {
#pragma unroll
  for (int o = 32; o > 0; o >>= 1) v += __shfl_down(v, o, 64);
  if ((tid & 63) == 0) scratch[tid >> 6] = v;
  __syncthreads();
  float r = (scratch[0] + scratch[1]) + (scratch[2] + scratch[3]);
  __syncthreads();
  return r;
}

// ---------------- K0: bank-mix coefficients ----------------
__global__ __launch_bounds__(256) void prep_kernel(
    const float* __restrict__ st_imp, const float* __restrict__ lt_imp,
    float* __restrict__ scal) {
  __shared__ float scr[4];
  int tid = threadIdx.x;
  float s = 0.f, l = 0.f;
  for (int i = tid; i < CST; i += 256) s += st_imp[i];
  for (int i = tid; i < CLT; i += 256) l += lt_imp[i];
  float ssum = block_sum_f(s, scr, tid);
  float lsum = block_sum_f(l, scr, tid);
  if (tid == 0) {
    float sw = 1.f / (1.f + __expf(-(ssum / CST)));
    float lw = 1.f / (1.f + __expf(-(lsum / CLT)));
    float tot = sw + lw;
    scal[0] = sw / tot;
    scal[1] = lw / tot;
  }
}

// ---------------- K1: Q = X @ Wq + bq ----------------
__global__ __launch_bounds__(256) void qproj_kernel(
    const float* __restrict__ X, const float* __restrict__ Wq,
    const float* __restrict__ bq, float* __restrict__ Qout) {
  __shared__ float xs[4][CD];
  int tid = threadIdx.x;
  int row0 = blockIdx.x * 4;
#pragma unroll
  for (int r = 0; r < 4; ++r)
    for (int dd = tid; dd < CD; dd += 256)
      xs[r][dd] = X[(size_t)(row0 + r) * CD + dd];
  __syncthreads();

  float acc[4][4];
#pragma unroll
  for (int r = 0; r < 4; ++r)
#pragma unroll
    for (int j = 0; j < 4; ++j) acc[r][j] = 0.f;

  int j0 = tid * 4;
  for (int dd = 0; dd < CD; dd += 2) {
    float4 w0 = *(const float4*)&Wq[(size_t)dd * CD + j0];
    float4 w1 = *(const float4*)&Wq[(size_t)(dd + 1) * CD + j0];
#pragma unroll
    for (int r = 0; r < 4; ++r) {
      float x0 = xs[r][dd], x1 = xs[r][dd + 1];
      acc[r][0] += x0 * w0.x + x1 * w1.x;
      acc[r][1] += x0 * w0.y + x1 * w1.y;
      acc[r][2] += x0 * w0.z + x1 * w1.z;
      acc[r][3] += x0 * w0.w + x1 * w1.w;
    }
  }
  float4 bb = *(const float4*)&bq[j0];
#pragma unroll
  for (int r = 0; r < 4; ++r) {
    float4 o;
    o.x = acc[r][0] + bb.x;
    o.y = acc[r][1] + bb.y;
    o.z = acc[r][2] + bb.z;
    o.w = acc[r][3] + bb.w;
    *(float4*)&Qout[(size_t)(row0 + r) * CD + j0] = o;
  }
}

// ---------------- K-transpose: K[m][h*64+d] (f32) -> KT[(h*64+d)][m] (bf16) ----
template <int M>
__global__ __launch_bounds__(256) void ktrans_kernel(
    const float* __restrict__ K, ushort_t* __restrict__ KT) {
  __shared__ float ts[64][65];
  int tid = threadIdx.x;
  int mt = blockIdx.x % (M / 64);
  int h = blockIdx.x / (M / 64);
  int m0 = mt * 64;

#pragma unroll
  for (int p = 0; p < 4; ++p) {
    int ml = p * 16 + (tid >> 4);
    int dc = (tid & 15) * 4;
    float4 v = *(const float4*)&K[(size_t)(m0 + ml) * CD + h * CHD + dc];
    ts[ml][dc] = v.x; ts[ml][dc + 1] = v.y; ts[ml][dc + 2] = v.z; ts[ml][dc + 3] = v.w;
  }
  __syncthreads();

  int d = tid >> 2;
  int mg = (tid & 3) * 16;
  unsigned pk[8];
#pragma unroll
  for (int i = 0; i < 8; ++i) {
    ushort_t lo = f2bf(ts[mg + 2 * i][d]);
    ushort_t hi = f2bf(ts[mg + 2 * i + 1][d]);
    pk[i] = (unsigned)lo | ((unsigned)hi << 16);
  }
  ushort_t* dst = KT + (size_t)(h * CHD + d) * M + m0 + mg;
  *(uint4*)dst = make_uint4(pk[0], pk[1], pk[2], pk[3]);
  *(uint4*)(dst + 8) = make_uint4(pk[4], pk[5], pk[6], pk[7]);
}

// wave-level select helper: given 256-bin histogram, find largest bin with
// suffix-count >= kk; returns (bin, remaining k within bin).
__device__ __forceinline__ int2 wave_hist_select(const int* histw, int l, int kk) {
  int4 c = *(const int4*)&histw[4 * l];
  int suf = c.x + c.y + c.z + c.w;
#pragma unroll
  for (int off = 1; off < 64; off <<= 1) {
    int t = __shfl_down(suf, off, 64);
    suf += (l + off < 64) ? t : 0;
  }
  unsigned long long bal = __ballot(suf >= kk);
  int L = 63 - __builtin_clzll(bal);
  int snL = __shfl(suf, (L + 1) & 63, 64);
  int sufL1 = (L == 63) ? 0 : snL;
  int cy = __shfl(c.y, L, 64);
  int cz = __shfl(c.z, L, 64);
  int cw = __shfl(c.w, L, 64);
  int s3 = cw + sufL1, s2 = cz + s3, s1 = cy + s2;
  int bin, rem;
  if (s3 >= kk)      { bin = 4 * L + 3; rem = kk - sufL1; }
  else if (s2 >= kk) { bin = 4 * L + 2; rem = kk - s3; }
  else if (s1 >= kk) { bin = 4 * L + 1; rem = kk - s2; }
  else               { bin = 4 * L;     rem = kk - s1; }
  return make_int2(bin, rem);
}

// ---------------- K2 v5: 512 threads (8 waves), 4 queries/block --------------
// Phase 1: c-outer register-blocked scores (acc[NG][4][4]), walking K pointer.
// Phase 2: wave (wq=w&3, half=w>>2): scores in regs; hist select; ballot
// compaction into per-half il segments (no count pass).
// w-fill: exp once per selected row, w overwrites sc_l (bf16), wsum here.
// Phase 3: PV reads w directly, 32-bit offset V loads.
template <int M, int LCAP>
__global__ __launch_bounds__(512, 4) void attn_v5(
    const float* __restrict__ Q, const ushort_t* __restrict__ KT,
    const float* __restrict__ Vp, const float* __restrict__ imp,
    const float* __restrict__ scal, int scal_idx, int kth,
    float* __restrict__ mem_out, int add_to) {
  constexpr int NG = M / 2048;    // groups of 256 per wave strip
  constexpr int NJ = M / 512;     // reg-resident uint2 per lane in phase 2
  constexpr int HC = LCAP / 2;    // per-half list capacity

  __shared__ ushort_t sc_l[4][M];
  __shared__ ushort_t il[4][2][HC];
  __shared__ int hist1[4][256];
  __shared__ int hist2[4][256];
  __shared__ float q_l[4][CHD];
  __shared__ float wmax[8][4];
  __shared__ float wsp[4][2];
  __shared__ float pacc[4][2][CHD];

  int tid = threadIdx.x;
  int l = tid & 63;
  int w = tid >> 6;        // 0..7
  int wq = w & 3;          // query this wave serves in phase 2/3
  int half = w >> 2;       // 0/1: which half of M
  int idx = blockIdx.x;
  int sg = idx & (CS / 4 - 1);
  int h = (idx >> 7) & (CH - 1);
  int b = idx >> 11;
  int s0 = sg * 4;
  int h6 = h * CHD;

  ((int*)hist1)[tid] = 0;
  ((int*)hist1)[tid + 512] = 0;
  ((int*)hist2)[tid] = 0;
  ((int*)hist2)[tid + 512] = 0;
  if (tid < 256)
    q_l[tid >> 6][tid & 63] = Q[((size_t)(b * CS + s0 + (tid >> 6))) * CD + h6 + (tid & 63)];
  __syncthreads();

  // ---- phase 1: scores over strip [w*M/8, (w+1)*M/8) ----
  float acc[NG][4][4];
#pragma unroll
  for (int g = 0; g < NG; ++g)
#pragma unroll
    for (int i = 0; i < 4; ++i)
#pragma unroll
      for (int q = 0; q < 4; ++q) acc[g][i][q] = 0.f;

  {
    const ushort_t* kp = KT + (size_t)h6 * M + w * (M / 8) + 4 * l;
#pragma unroll
    for (int c = 0; c < 16; ++c) {
      float4 qf[4];
#pragma unroll
      for (int q = 0; q < 4; ++q) qf[q] = *(const float4*)&q_l[q][c * 4];
#pragma unroll
      for (int dd = 0; dd < 4; ++dd) {
#pragma unroll
        for (int g = 0; g < NG; ++g) {
          uint2 ka = *(const uint2*)(kp + g * 256);
          float k0 = u2f(ka.x << 16), k1 = u2f(ka.x & 0xFFFF0000u);
          float k2 = u2f(ka.y << 16), k3 = u2f(ka.y & 0xFFFF0000u);
#pragma unroll
          for (int q = 0; q < 4; ++q) {
            float qq = (dd == 0) ? qf[q].x : (dd == 1) ? qf[q].y
                     : (dd == 2) ? qf[q].z : qf[q].w;
            acc[g][0][q] += k0 * qq;
            acc[g][1][q] += k1 * qq;
            acc[g][2][q] += k2 * qq;
            acc[g][3][q] += k3 * qq;
          }
        }
        kp += M;
      }
    }
  }

  float lmax[4] = {-1e30f, -1e30f, -1e30f, -1e30f};
#pragma unroll
  for (int g = 0; g < NG; ++g) {
    int mA = w * (M / 8) + g * 256 + 4 * l;
    float4 ip = *(const float4*)&imp[mA];
#pragma unroll
    for (int q = 0; q < 4; ++q) {
      float s0v = acc[g][0][q] * 0.125f * ip.x;
      float s1v = acc[g][1][q] * 0.125f * ip.y;
      float s2v = acc[g][2][q] * 0.125f * ip.z;
      float s3v = acc[g][3][q] * 0.125f * ip.w;
      lmax[q] = fmaxf(lmax[q], fmaxf(fmaxf(s0v, s1v), fmaxf(s2v, s3v)));
      unsigned p0 = (unsigned)f2bf(s0v) | ((unsigned)f2bf(s1v) << 16);
      unsigned p1 = (unsigned)f2bf(s2v) | ((unsigned)f2bf(s3v) << 16);
      *(uint2*)&sc_l[q][mA] = make_uint2(p0, p1);
    }
  }
#pragma unroll
  for (int q = 0; q < 4; ++q) {
    float v = lmax[q];
#pragma unroll
    for (int off = 32; off > 0; off >>= 1) v = fmaxf(v, __shfl_down(v, off, 64));
    if (l == 0) wmax[w][q] = v;
  }
  __syncthreads();

  // global max for this wave's query
  float t = wmax[0][wq];
#pragma unroll
  for (int ww = 1; ww < 8; ++ww) t = fmaxf(t, wmax[ww][wq]);

  // ---- phase 2: scores into regs (one LDS pass), then reg-resident select ----
  int ms = half * (M / 2);
  unsigned sreg[NJ][2];
#pragma unroll
  for (int j = 0; j < NJ; ++j) {
    uint2 sv = *(const uint2*)&sc_l[wq][ms + j * 256 + 4 * l];
    sreg[j][0] = sv.x;
    sreg[j][1] = sv.y;
  }

  // hist level 1 (high 8 bits of mono16)
#pragma unroll
  for (int j = 0; j < NJ; ++j) {
    atomicAdd(&hist1[wq][mono16((ushort_t)(sreg[j][0] & 0xFFFF)) >> 8], 1);
    atomicAdd(&hist1[wq][mono16((ushort_t)(sreg[j][0] >> 16)) >> 8], 1);
    atomicAdd(&hist1[wq][mono16((ushort_t)(sreg[j][1] & 0xFFFF)) >> 8], 1);
    atomicAdd(&hist1[wq][mono16((ushort_t)(sreg[j][1] >> 16)) >> 8], 1);
  }
  __syncthreads();
  int2 sel1 = wave_hist_select(hist1[wq], l, kth);
  int b1 = sel1.x;

  // hist level 2 (low 8 bits within bucket b1)
#pragma unroll
  for (int j = 0; j < NJ; ++j) {
#pragma unroll
    for (int e = 0; e < 4; ++e) {
      ushort_t u = (ushort_t)(sreg[j][e >> 1] >> ((e & 1) * 16));
      int mn = mono16(u);
      if ((mn >> 8) == b1) atomicAdd(&hist2[wq][mn & 0xFF], 1);
    }
  }
  __syncthreads();
  int2 sel2 = wave_hist_select(hist2[wq], l, sel1.y);
  int thr = (b1 << 8) | sel2.x;

  // ---- single compaction pass (count folded in) ----
  unsigned long long lt_mask = (1ull << l) - 1ull;
  int pos = 0;
#pragma unroll
  for (int j = 0; j < NJ; ++j) {
#pragma unroll
    for (int e = 0; e < 4; ++e) {
      ushort_t u = (ushort_t)(sreg[j][e >> 1] >> ((e & 1) * 16));
      bool sel = mono16(u) >= thr;
      unsigned long long mask = __ballot(sel);
      if (sel) {
        int p = pos + __builtin_popcountll(mask & lt_mask);
        if (p < HC) il[wq][half][p] = (ushort_t)(ms + j * 256 + 4 * l + e);
      }
      pos += __builtin_popcountll(mask);
    }
  }
  int nhalf = pos < HC ? pos : HC;

  // ---- w-fill: exp once per selected row; overwrite sc_l with bf16 w ----
  float wsum = 0.f;
  for (int i = l; i < nhalf; i += 64) {
    int m = il[wq][half][i];
    float wv = __expf(bf2f(sc_l[wq][m]) - t);
    wsum += wv;
    sc_l[wq][m] = f2bf(wv);
  }
#pragma unroll
  for (int off = 32; off > 0; off >>= 1) wsum += __shfl_down(wsum, off, 64);
  if (l == 0) wsp[wq][half] = wsum;

  // ---- phase 3: PV over this half's selected rows ----
  {
    const float* Vb = Vp + h6;  // uniform base; per-lane 32-bit element index
    float acc3 = 0.f;
    int i = 0;
    for (; i + 4 <= nhalf; i += 4) {
      uint2 pk = *(const uint2*)&il[wq][half][i];
      int m0 = pk.x & 0xFFFF, m1 = pk.x >> 16;
      int m2 = pk.y & 0xFFFF, m3 = pk.y >> 16;
      float w0 = bf2f(sc_l[wq][m0]);
      float w1 = bf2f(sc_l[wq][m1]);
      float w2 = bf2f(sc_l[wq][m2]);
      float w3 = bf2f(sc_l[wq][m3]);
      float v0 = Vb[(unsigned)(m0 << 10) + l];
      float v1 = Vb[(unsigned)(m1 << 10) + l];
      float v2 = Vb[(unsigned)(m2 << 10) + l];
      float v3 = Vb[(unsigned)(m3 << 10) + l];
      acc3 += w0 * v0 + w1 * v1 + w2 * v2 + w3 * v3;
    }
    for (; i < nhalf; ++i) {
      int m0 = il[wq][half][i];
      acc3 += bf2f(sc_l[wq][m0]) * Vb[(unsigned)(m0 << 10) + l];
    }
    pacc[wq][half][l] = acc3;
  }
  __syncthreads();
  if (half == 0) {
    float o = (pacc[wq][0][l] + pacc[wq][1][l]) *
              (scal[scal_idx] / (wsp[wq][0] + wsp[wq][1]));
    size_t off = ((size_t)(b * CS + s0 + wq)) * CD + h6 + l;
    if (add_to) mem_out[off] += o;
    else mem_out[off] = o;
  }
}

// ---------------- K2 v2 (fallback if ws too small) ----------
template <int M, int NPT, int LCAP>
__global__ __launch_bounds__(256) void attn_v2(
    const float* __restrict__ Q, const float* __restrict__ Kp,
    const float* __restrict__ Vp, const float* __restrict__ imp,
    const float* __restrict__ scal, int scal_idx, int kth,
    float* __restrict__ mem_out, int add_to) {
  __shared__ float q_l[4][CHD];
  __shared__ ushort_t sc_l[4][M];
  __shared__ ushort_t il[4][LCAP];
  __shared__ int hist[256];
  __shared__ int hc[256];
  __shared__ float fscr[4];
  __shared__ int iscr[4];
  __shared__ int bsel, ksel;

  int tid = threadIdx.x;
  int idx = blockIdx.x;
  int sg = idx & (CS / 4 - 1);
  int h = (idx >> 7) & (CH - 1);
  int b = idx >> 11;
  int s0 = sg * 4;

  {
    int qi = tid >> 6, d = tid & 63;
    q_l[qi][d] = Q[((size_t)(b * CS + s0 + qi)) * CD + h * CHD + d];
  }
  __syncthreads();

  float lmax0 = -1e30f, lmax1 = -1e30f, lmax2 = -1e30f, lmax3 = -1e30f;
  for (int j0 = 0; j0 < NPT; j0 += 2) {
    int m0 = tid + j0 * 256;
    int m1 = m0 + 256;
    float a00 = 0, a01 = 0, a10 = 0, a11 = 0, a20 = 0, a21 = 0, a30 = 0, a31 = 0;
#pragma unroll
    for (int qt = 0; qt < 4; ++qt) {
      const float4* r0 = (const float4*)(Kp + (size_t)m0 * CD + h * CHD + qt * 16);
      const float4* r1 = (const float4*)(Kp + (size_t)m1 * CD + h * CHD + qt * 16);
      float4 kA[4], kB[4];
#pragma unroll
      for (int c = 0; c < 4; ++c) { kA[c] = r0[c]; kB[c] = r1[c]; }
#pragma unroll
      for (int c = 0; c < 4; ++c) {
        float4 q0 = *(const float4*)&q_l[0][qt * 16 + c * 4];
        float4 q1 = *(const float4*)&q_l[1][qt * 16 + c * 4];
        float4 q2 = *(const float4*)&q_l[2][qt * 16 + c * 4];
        float4 q3 = *(const float4*)&q_l[3][qt * 16 + c * 4];
        a00 += kA[c].x * q0.x + kA[c].y * q0.y + kA[c].z * q0.z + kA[c].w * q0.w;
        a01 += kB[c].x * q0.x + kB[c].y * q0.y + kB[c].z * q0.z + kB[c].w * q0.w;
        a10 += kA[c].x * q1.x + kA[c].y * q1.y + kA[c].z * q1.z + kA[c].w * q1.w;
        a11 += kB[c].x * q1.x + kB[c].y * q1.y + kB[c].z * q1.z + kB[c].w * q1.w;
        a20 += kA[c].x * q2.x + kA[c].y * q2.y + kA[c].z * q2.z + kA[c].w * q2.w;
        a21 += kB[c].x * q2.x + kB[c].y * q2.y + kB[c].z * q2.z + kB[c].w * q2.w;
        a30 += kA[c].x * q3.x + kA[c].y * q3.y + kA[c].z * q3.z + kA[c].w * q3.w;
        a31 += kB[c].x * q3.x + kB[c].y * q3.y + kB[c].z * q3.z + kB[c].w * q3.w;
      }
    }
    float f0 = 0.125f * imp[m0], f1 = 0.125f * imp[m1];
    float s00 = a00 * f0, s01 = a01 * f1;
    float s10 = a10 * f0, s11 = a11 * f1;
    float s20 = a20 * f0, s21 = a21 * f1;
    float s30 = a30 * f0, s31 = a31 * f1;
    sc_l[0][m0] = f2bf(s00); sc_l[0][m1] = f2bf(s01);
    sc_l[1][m0] = f2bf(s10); sc_l[1][m1] = f2bf(s11);
    sc_l[2][m0] = f2bf(s20); sc_l[2][m1] = f2bf(s21);
    sc_l[3][m0] = f2bf(s30); sc_l[3][m1] = f2bf(s31);
    lmax0 = fmaxf(lmax0, fmaxf(s00, s01));
    lmax1 = fmaxf(lmax1, fmaxf(s10, s11));
    lmax2 = fmaxf(lmax2, fmaxf(s20, s21));
    lmax3 = fmaxf(lmax3, fmaxf(s30, s31));
  }

  float gmaxr[4];
  {
    __shared__ float fs2[4];
#pragma unroll
    for (int q = 0; q < 4; ++q) {
      float v = (q == 0) ? lmax0 : (q == 1) ? lmax1 : (q == 2) ? lmax2 : lmax3;
#pragma unroll
      for (int o = 32; o > 0; o >>= 1) v = fmaxf(v, __shfl_down(v, o, 64));
      if ((tid & 63) == 0) fs2[tid >> 6] = v;
      __syncthreads();
      gmaxr[q] = fmaxf(fmaxf(fs2[0], fs2[1]), fmaxf(fs2[2], fs2[3]));
      __syncthreads();
    }
  }

  float wsumr[4];
  int nselr[4];

  for (int qi = 0; qi < 4; ++qi) {
    hist[tid] = 0;
    __syncthreads();
#pragma unroll
    for (int j = 0; j < NPT; ++j) {
      ushort_t u = sc_l[qi][tid + j * 256];
      atomicAdd(&hist[mono16(u) >> 8], 1);
    }
    __syncthreads();
    hc[tid] = hist[tid];
    __syncthreads();
#pragma unroll
    for (int off = 1; off < 256; off <<= 1) {
      int add = (tid + off < 256) ? hc[tid + off] : 0;
      __syncthreads();
      hc[tid] += add;
      __syncthreads();
    }
    if (hc[tid] >= kth && (tid == 255 || hc[tid + 1] < kth)) {
      bsel = tid;
      ksel = kth - (tid == 255 ? 0 : hc[tid + 1]);
    }
    __syncthreads();
    int b1 = bsel, kp = ksel;
    __syncthreads();
    hist[tid] = 0;
    __syncthreads();
#pragma unroll
    for (int j = 0; j < NPT; ++j) {
      int mn = mono16(sc_l[qi][tid + j * 256]);
      if ((mn >> 8) == b1) atomicAdd(&hist[mn & 0xFF], 1);
    }
    __syncthreads();
    hc[tid] = hist[tid];
    __syncthreads();
#pragma unroll
    for (int off = 1; off < 256; off <<= 1) {
      int add = (tid + off < 256) ? hc[tid + off] : 0;
      __syncthreads();
      hc[tid] += add;
      __syncthreads();
    }
    if (hc[tid] >= kp && (tid == 255 || hc[tid + 1] < kp)) bsel = tid;
    __syncthreads();
    int thr = (b1 << 8) | bsel;
    __syncthreads();

    float gm = gmaxr[qi];
    int cnt = 0;
    float ws = 0.f;
#pragma unroll
    for (int j = 0; j < NPT; ++j) {
      ushort_t u = sc_l[qi][tid + j * 256];
      if (mono16(u) >= thr) {
        cnt++;
        ws += __expf(bf2f(u) - gm);
      }
    }
    int lane = tid & 63, wv = tid >> 6;
    int v = cnt;
#pragma unroll
    for (int off = 1; off < 64; off <<= 1) {
      int tt = __shfl_up(v, off, 64);
      if (lane >= off) v += tt;
    }
    if (lane == 63) iscr[wv] = v;
    __syncthreads();
    int base = 0;
#pragma unroll
    for (int ww = 0; ww < 4; ++ww)
      if (ww < wv) base += iscr[ww];
    int pos = base + v - cnt;
    int ntot = iscr[0] + iscr[1] + iscr[2] + iscr[3];
    __syncthreads();
#pragma unroll
    for (int j = 0; j < NPT; ++j) {
      int m = tid + j * 256;
      ushort_t u = sc_l[qi][m];
      if (mono16(u) >= thr) {
        if (pos < LCAP) il[qi][pos] = (ushort_t)m;
        pos++;
      }
    }
    wsumr[qi] = block_sum_f(ws, fscr, tid);
    nselr[qi] = ntot < LCAP ? ntot : LCAP;
    __syncthreads();
  }

  {
    int wv = tid >> 6, d = tid & 63;
    float gm = gmaxr[wv];
    float wsc = scal[scal_idx] / wsumr[wv];
    int n = nselr[wv];
    const float* Vh = Vp + h * CHD + d;
    float acc = 0.f;
    int i = 0;
    for (; i + 4 <= n; i += 4) {
      int m0 = il[wv][i], m1 = il[wv][i + 1], m2 = il[wv][i + 2], m3 = il[wv][i + 3];
      float v0 = Vh[(size_t)m0 * CD];
      float v1 = Vh[(size_t)m1 * CD];
      float v2 = Vh[(size_t)m2 * CD];
      float v3 = Vh[(size_t)m3 * CD];
      float w0 = __expf(bf2f(sc_l[wv][m0]) - gm);
      float w1 = __expf(bf2f(sc_l[wv][m1]) - gm);
      float w2 = __expf(bf2f(sc_l[wv][m2]) - gm);
      float w3 = __expf(bf2f(sc_l[wv][m3]) - gm);
      acc += w0 * v0 + w1 * v1 + w2 * v2 + w3 * v3;
    }
    for (; i < n; ++i) {
      int m0 = il[wv][i];
      acc += __expf(bf2f(sc_l[wv][m0]) - gm) * Vh[(size_t)m0 * CD];
    }
    size_t off = ((size_t)(b * CS + s0 + wv)) * CD + h * CHD + d;
    float o = acc * wsc;
    if (add_to) mem_out[off] += o;
    else mem_out[off] = o;
  }
}

// ---------------- K3: gate + residual + LayerNorm ----------------
__global__ __launch_bounds__(256) void gate_ln_kernel(
    const float* __restrict__ X, const float* __restrict__ Mem,
    const float* __restrict__ Wg, const float* __restrict__ bg,
    const float* __restrict__ lng, const float* __restrict__ lnb,
    float* __restrict__ Out) {
  __shared__ float scr[4];
  int tid = threadIdx.x;
  int row = blockIdx.x;
  int d0 = tid * 4;

  float4 px = *(const float4*)(X + (size_t)row * CD + d0);
  float4 pm = *(const float4*)(Mem + (size_t)row * CD + d0);
  float4 wi = *(const float4*)(Wg + d0);
  float4 wm = *(const float4*)(Wg + CD + d0);

  float t = px.x * wi.x + px.y * wi.y + px.z * wi.z + px.w * wi.w +
            pm.x * wm.x + pm.y * wm.y + pm.z * wm.z + pm.w * wm.w;
  float z = block_sum_f(t, scr, tid) + bg[0];
  float gate = 1.f / (1.f + __expf(-z));

  float xr0 = px.x + pm.x * gate;
  float xr1 = px.y + pm.y * gate;
  float xr2 = px.z + pm.z * gate;
  float xr3 = px.w + pm.w * gate;

  float ssum = block_sum_f(xr0 + xr1 + xr2 + xr3, scr, tid);
  float ssq = block_sum_f(xr0 * xr0 + xr1 * xr1 + xr2 * xr2 + xr3 * xr3, scr, tid);
  float mu = ssum * (1.f / CD);
  float var = ssq * (1.f / CD) - mu * mu;
  float inv = rsqrtf(var + 1e-5f);

  float4 pg = *(const float4*)(lng + d0);
  float4 pb = *(const float4*)(lnb + d0);
  float4 o;
  o.x = (xr0 - mu) * inv * pg.x + pb.x;
  o.y = (xr1 - mu) * inv * pg.y + pb.y;
  o.z = (xr2 - mu) * inv * pg.z + pb.z;
  o.w = (xr3 - mu) * inv * pg.w + pb.w;
  *(float4*)(Out + (size_t)row * CD + d0) = o;
}

extern "C" void kernel_launch(void* const* d_in, const int* in_sizes, int n_in,
                              void* d_out, int out_size, void* d_ws, size_t ws_size,
                              hipStream_t stream) {
  const float* inputs = (const float*)d_in[0];
  const float* Wq = (const float*)d_in[1];
  const float* bq = (const float*)d_in[2];
  const float* st_keys = (const float*)d_in[3];
  const float* st_values = (const float*)d_in[4];
  const float* lt_keys = (const float*)d_in[5];
  const float* lt_values = (const float*)d_in[6];
  const float* st_imp = (const float*)d_in[7];
  const float* lt_imp = (const float*)d_in[8];
  const float* Wg = (const float*)d_in[9];
  const float* bg = (const float*)d_in[10];
  const float* ln_g = (const float*)d_in[11];
  const float* ln_b = (const float*)d_in[12];
  float* out = (float*)d_out;

  size_t nQ = (size_t)CB * CS * CD;
  float* Qws = (float*)d_ws;
  float* Memws = Qws + nQ;
  float* scal = Memws + nQ;
  ushort_t* KTst = (ushort_t*)(scal + 64);
  ushort_t* KTlt = KTst + (size_t)CD * CST;
  size_t need = (size_t)((char*)(KTlt + (size_t)CD * CLT) - (char*)d_ws);

  int nblk = CB * CH * (CS / 4);  // 4096

  prep_kernel<<<1, 256, 0, stream>>>(st_imp, lt_imp, scal);
  qproj_kernel<<<CB * CS / 4, 256, 0, stream>>>(inputs, Wq, bq, Qws);

  if (ws_size >= need) {
    ktrans_kernel<CST><<<(CST / 64) * CH, 256, 0, stream>>>(st_keys, KTst);
    ktrans_kernel<CLT><<<(CLT / 64) * CH, 256, 0, stream>>>(lt_keys, KTlt);
    attn_v5<CST, 512><<<nblk, 512, 0, stream>>>(
        Qws, KTst, st_values, st_imp, scal, 0, CKST, Memws, 0);
    attn_v5<CLT, 1024><<<nblk, 512, 0, stream>>>(
        Qws, KTlt, lt_values, lt_imp, scal, 1, CKLT, Memws, 1);
  } else {
    attn_v2<CST, CST / 256, 512><<<nblk, 256, 0, stream>>>(
        Qws, st_keys, st_values, st_imp, scal, 0, CKST, Memws, 0);
    attn_v2<CLT, CLT / 256, 1024><<<nblk, 256, 0, stream>>>(
        Qws, lt_keys, lt_values, lt_imp, scal, 1, CKLT, Memws, 1);
  }
  gate_ln_kernel<<<CB * CS, 256, 0, stream>>>(inputs, Memws, Wg, bg, ln_g, ln_b, out);
}

// Round 9
// 1230.588 us; speedup vs baseline: 1.1807x; 1.1807x over previous
//
#include <hip/hip_runtime.h>
#include <hip/hip_bf16.h>

typedef unsigned short ushort_t;

constexpr int CB = 2, CS = 512, CD = 1024, CH = 16, CHD = 64;
constexpr int CST = 2048, CLT = 6144;
constexpr int CKST = 204, CKLT = 614;

__device__ __forceinline__ float u2f(unsigned u) { return __uint_as_float(u); }
__device__ __forceinline__ float bf2f(ushort_t u) {
  return __uint_as_float(((unsigned)u) << 16);
}
__device__ __forceinline__ ushort_t f2bf(float f) {
  __hip_bfloat16 h = __float2bfloat16(f);
  return *reinterpret_cast<ushort_t*>(&h);
}
// monotone 16-bit key: mono(a) > mono(b) <=> bf16 a > b
__device__ __forceinline__ unsigned mono16(ushort_t u) {
  return (u & 0x8000) ? (unsigned)((ushort_t)~u) : (unsigned)(u | 0x8000);
}

__device__ __forceinline__ float block_sum_f(float v, float* scratch, int tid) {
#pragma unroll
  for (int o = 32; o > 0; o >>= 1) v += __shfl_down(v, o, 64);
  if ((tid & 63) == 0) scratch[tid >> 6] = v;
  __syncthreads();
  float r = (scratch[0] + scratch[1]) + (scratch[2] + scratch[3]);
  __syncthreads();
  return r;
}

// ---------------- K0: bank-mix coefficients ----------------
__global__ __launch_bounds__(256) void prep_kernel(
    const float* __restrict__ st_imp, const float* __restrict__ lt_imp,
    float* __restrict__ scal) {
  __shared__ float scr[4];
  int tid = threadIdx.x;
  float s = 0.f, l = 0.f;
  for (int i = tid; i < CST; i += 256) s += st_imp[i];
  for (int i = tid; i < CLT; i += 256) l += lt_imp[i];
  float ssum = block_sum_f(s, scr, tid);
  float lsum = block_sum_f(l, scr, tid);
  if (tid == 0) {
    float sw = 1.f / (1.f + __expf(-(ssum / CST)));
    float lw = 1.f / (1.f + __expf(-(lsum / CLT)));
    float tot = sw + lw;
    scal[0] = sw / tot;
    scal[1] = lw / tot;
  }
}

// ---------------- K1: Q = X @ Wq + bq ----------------
__global__ __launch_bounds__(256) void qproj_kernel(
    const float* __restrict__ X, const float* __restrict__ Wq,
    const float* __restrict__ bq, float* __restrict__ Qout) {
  __shared__ float xs[4][CD];
  int tid = threadIdx.x;
  int row0 = blockIdx.x * 4;
#pragma unroll
  for (int r = 0; r < 4; ++r)
    for (int dd = tid; dd < CD; dd += 256)
      xs[r][dd] = X[(size_t)(row0 + r) * CD + dd];
  __syncthreads();

  float acc[4][4];
#pragma unroll
  for (int r = 0; r < 4; ++r)
#pragma unroll
    for (int j = 0; j < 4; ++j) acc[r][j] = 0.f;

  int j0 = tid * 4;
  for (int dd = 0; dd < CD; dd += 2) {
    float4 w0 = *(const float4*)&Wq[(size_t)dd * CD + j0];
    float4 w1 = *(const float4*)&Wq[(size_t)(dd + 1) * CD + j0];
#pragma unroll
    for (int r = 0; r < 4; ++r) {
      float x0 = xs[r][dd], x1 = xs[r][dd + 1];
      acc[r][0] += x0 * w0.x + x1 * w1.x;
      acc[r][1] += x0 * w0.y + x1 * w1.y;
      acc[r][2] += x0 * w0.z + x1 * w1.z;
      acc[r][3] += x0 * w0.w + x1 * w1.w;
    }
  }
  float4 bb = *(const float4*)&bq[j0];
#pragma unroll
  for (int r = 0; r < 4; ++r) {
    float4 o;
    o.x = acc[r][0] + bb.x;
    o.y = acc[r][1] + bb.y;
    o.z = acc[r][2] + bb.z;
    o.w = acc[r][3] + bb.w;
    *(float4*)&Qout[(size_t)(row0 + r) * CD + j0] = o;
  }
}

// ---------------- K-transpose: K[m][h*64+d] (f32) -> KT[(h*64+d)][m] (bf16) ----
template <int M>
__global__ __launch_bounds__(256) void ktrans_kernel(
    const float* __restrict__ K, ushort_t* __restrict__ KT) {
  __shared__ float ts[64][65];
  int tid = threadIdx.x;
  int mt = blockIdx.x % (M / 64);
  int h = blockIdx.x / (M / 64);
  int m0 = mt * 64;

#pragma unroll
  for (int p = 0; p < 4; ++p) {
    int ml = p * 16 + (tid >> 4);
    int dc = (tid & 15) * 4;
    float4 v = *(const float4*)&K[(size_t)(m0 + ml) * CD + h * CHD + dc];
    ts[ml][dc] = v.x; ts[ml][dc + 1] = v.y; ts[ml][dc + 2] = v.z; ts[ml][dc + 3] = v.w;
  }
  __syncthreads();

  int d = tid >> 2;
  int mg = (tid & 3) * 16;
  unsigned pk[8];
#pragma unroll
  for (int i = 0; i < 8; ++i) {
    ushort_t lo = f2bf(ts[mg + 2 * i][d]);
    ushort_t hi = f2bf(ts[mg + 2 * i + 1][d]);
    pk[i] = (unsigned)lo | ((unsigned)hi << 16);
  }
  ushort_t* dst = KT + (size_t)(h * CHD + d) * M + m0 + mg;
  *(uint4*)dst = make_uint4(pk[0], pk[1], pk[2], pk[3]);
  *(uint4*)(dst + 8) = make_uint4(pk[4], pk[5], pk[6], pk[7]);
}

// ---------------- K2 v6: 512 threads (8 waves), 4 queries/block --------------
// Phase 1: round-6 g-outer scores (acc[4][4] per group, no spill).
// Select: register-resident mono16 keys + 16-iter binary search; wave pair
// (wq, half) combines counts via double-buffered LDS slot (1 barrier/iter).
// No LDS atomics. Ballot compaction, exp-hoisted w-fill, 32-bit-offset PV.
template <int M, int LCAP>
__global__ __launch_bounds__(512, 4) void attn_v6(
    const float* __restrict__ Q, const ushort_t* __restrict__ KT,
    const float* __restrict__ Vp, const float* __restrict__ imp,
    const float* __restrict__ scal, int scal_idx, int kth,
    float* __restrict__ mem_out, int add_to) {
  constexpr int NG = M / 2048;  // score groups of 256 per wave strip
  constexpr int NJ = M / 512;   // uint2 per lane covering this wave's half
  constexpr int HC = LCAP / 2;  // per-half list capacity

  __shared__ ushort_t sc_l[4][M];
  __shared__ ushort_t il[4][2][HC];
  __shared__ float q_l[4][CHD];
  __shared__ float wmax[8][4];
  __shared__ int cntw[2][4][2];
  __shared__ float wsp[4][2];
  __shared__ float pacc[4][2][CHD];

  int tid = threadIdx.x;
  int l = tid & 63;
  int w = tid >> 6;        // 0..7
  int wq = w & 3;          // query this wave serves in select/PV
  int half = w >> 2;       // 0/1: which half of M
  int idx = blockIdx.x;
  int sg = idx & (CS / 4 - 1);
  int h = (idx >> 7) & (CH - 1);
  int b = idx >> 11;
  int s0 = sg * 4;
  int h6 = h * CHD;

  if (tid < 256)
    q_l[tid >> 6][tid & 63] = Q[((size_t)(b * CS + s0 + (tid >> 6))) * CD + h6 + (tid & 63)];
  __syncthreads();

  // ---- phase 1 (round-6 structure): scores over strip [w*M/8, (w+1)*M/8) ----
  float lmax[4] = {-1e30f, -1e30f, -1e30f, -1e30f};
#pragma unroll 1
  for (int g = 0; g < NG; ++g) {
    int mA = w * (M / 8) + g * 256 + 4 * l;
    float4 ip = *(const float4*)&imp[mA];
    float acc[4][4];
#pragma unroll
    for (int i = 0; i < 4; ++i)
#pragma unroll
      for (int q = 0; q < 4; ++q) acc[i][q] = 0.f;

#pragma unroll 4
    for (int c = 0; c < 16; ++c) {
      float qc[4][4];
#pragma unroll
      for (int q = 0; q < 4; ++q) {
        float4 t4 = *(const float4*)&q_l[q][c * 4];
        qc[q][0] = t4.x; qc[q][1] = t4.y; qc[q][2] = t4.z; qc[q][3] = t4.w;
      }
#pragma unroll
      for (int dd = 0; dd < 4; ++dd) {
        uint2 ka = *(const uint2*)(KT + (size_t)(h6 + c * 4 + dd) * M + mA);
        float k0 = u2f(ka.x << 16), k1 = u2f(ka.x & 0xFFFF0000u);
        float k2 = u2f(ka.y << 16), k3 = u2f(ka.y & 0xFFFF0000u);
#pragma unroll
        for (int q = 0; q < 4; ++q) {
          float qq = qc[q][dd];
          acc[0][q] += k0 * qq;
          acc[1][q] += k1 * qq;
          acc[2][q] += k2 * qq;
          acc[3][q] += k3 * qq;
        }
      }
    }
#pragma unroll
    for (int q = 0; q < 4; ++q) {
      float s0v = acc[0][q] * 0.125f * ip.x;
      float s1v = acc[1][q] * 0.125f * ip.y;
      float s2v = acc[2][q] * 0.125f * ip.z;
      float s3v = acc[3][q] * 0.125f * ip.w;
      lmax[q] = fmaxf(lmax[q], fmaxf(fmaxf(s0v, s1v), fmaxf(s2v, s3v)));
      unsigned p0 = (unsigned)f2bf(s0v) | ((unsigned)f2bf(s1v) << 16);
      unsigned p1 = (unsigned)f2bf(s2v) | ((unsigned)f2bf(s3v) << 16);
      *(uint2*)&sc_l[q][mA] = make_uint2(p0, p1);
    }
  }
#pragma unroll
  for (int q = 0; q < 4; ++q) {
    float v = lmax[q];
#pragma unroll
    for (int off = 32; off > 0; off >>= 1) v = fmaxf(v, __shfl_down(v, off, 64));
    if (l == 0) wmax[w][q] = v;
  }
  __syncthreads();

  // global max for this wave's query
  float t = wmax[0][wq];
#pragma unroll
  for (int ww = 1; ww < 8; ++ww) t = fmaxf(t, wmax[ww][wq]);

  // ---- load this half's scores once; keep mono16 keys in registers ----
  int ms = half * (M / 2);
  unsigned mreg[2 * NJ];
#pragma unroll
  for (int j = 0; j < NJ; ++j) {
    uint2 sv = *(const uint2*)&sc_l[wq][ms + j * 256 + 4 * l];
    mreg[2 * j] = mono16((ushort_t)(sv.x & 0xFFFF)) |
                  (mono16((ushort_t)(sv.x >> 16)) << 16);
    mreg[2 * j + 1] = mono16((ushort_t)(sv.y & 0xFFFF)) |
                      (mono16((ushort_t)(sv.y >> 16)) << 16);
  }

  // ---- 16-iter binary search for k-th-largest threshold (no atomics) ----
  unsigned lo = 0u, hi = 0xFFFFu;
#pragma unroll 1
  for (int it = 0; it < 16; ++it) {
    unsigned mid = lo + ((hi - lo + 1u) >> 1);
    int cnt = 0;
#pragma unroll
    for (int j = 0; j < 2 * NJ; ++j) {
      cnt += (int)((mreg[j] & 0xFFFFu) >= mid);
      cnt += (int)((mreg[j] >> 16) >= mid);
    }
#pragma unroll
    for (int off = 32; off > 0; off >>= 1) cnt += __shfl_down(cnt, off, 64);
    if (l == 0) cntw[it & 1][wq][half] = cnt;
    __syncthreads();
    int tot = cntw[it & 1][wq][0] + cntw[it & 1][wq][1];
    if (tot >= kth) lo = mid;
    else hi = mid - 1u;
  }
  unsigned thr = lo;

  // ---- single ballot compaction pass (from registers) ----
  unsigned long long lt_mask = (1ull << l) - 1ull;
  int pos = 0;
#pragma unroll
  for (int j = 0; j < NJ; ++j) {
#pragma unroll
    for (int e = 0; e < 4; ++e) {
      unsigned mv = (mreg[2 * j + (e >> 1)] >> ((e & 1) * 16)) & 0xFFFFu;
      bool sel = mv >= thr;
      unsigned long long mask = __ballot(sel);
      if (sel) {
        int p = pos + __builtin_popcountll(mask & lt_mask);
        if (p < HC) il[wq][half][p] = (ushort_t)(ms + j * 256 + 4 * l + e);
      }
      pos += __builtin_popcountll(mask);
    }
  }
  int nhalf = pos < HC ? pos : HC;

  // ---- w-fill: exp once per selected row; overwrite sc_l with bf16 w ----
  float wsum = 0.f;
  for (int i = l; i < nhalf; i += 64) {
    int m = il[wq][half][i];
    float wv = __expf(bf2f(sc_l[wq][m]) - t);
    wsum += wv;
    sc_l[wq][m] = f2bf(wv);
  }
#pragma unroll
  for (int off = 32; off > 0; off >>= 1) wsum += __shfl_down(wsum, off, 64);
  if (l == 0) wsp[wq][half] = wsum;

  // ---- PV over this half's selected rows ----
  {
    const float* Vb = Vp + h6;  // uniform base; per-lane 32-bit element index
    float acc3 = 0.f;
    int i = 0;
    for (; i + 4 <= nhalf; i += 4) {
      uint2 pk = *(const uint2*)&il[wq][half][i];
      int m0 = pk.x & 0xFFFF, m1 = pk.x >> 16;
      int m2 = pk.y & 0xFFFF, m3 = pk.y >> 16;
      float w0 = bf2f(sc_l[wq][m0]);
      float w1 = bf2f(sc_l[wq][m1]);
      float w2 = bf2f(sc_l[wq][m2]);
      float w3 = bf2f(sc_l[wq][m3]);
      float v0 = Vb[(unsigned)(m0 << 10) + l];
      float v1 = Vb[(unsigned)(m1 << 10) + l];
      float v2 = Vb[(unsigned)(m2 << 10) + l];
      float v3 = Vb[(unsigned)(m3 << 10) + l];
      acc3 += w0 * v0 + w1 * v1 + w2 * v2 + w3 * v3;
    }
    for (; i < nhalf; ++i) {
      int m0 = il[wq][half][i];
      acc3 += bf2f(sc_l[wq][m0]) * Vb[(unsigned)(m0 << 10) + l];
    }
    pacc[wq][half][l] = acc3;
  }
  __syncthreads();
  if (half == 0) {
    float o = (pacc[wq][0][l] + pacc[wq][1][l]) *
              (scal[scal_idx] / (wsp[wq][0] + wsp[wq][1]));
    size_t off = ((size_t)(b * CS + s0 + wq)) * CD + h6 + l;
    if (add_to) mem_out[off] += o;
    else mem_out[off] = o;
  }
}

// ---------------- K2 v2 (fallback if ws too small) ----------
template <int M, int NPT, int LCAP>
__global__ __launch_bounds__(256) void attn_v2(
    const float* __restrict__ Q, const float* __restrict__ Kp,
    const float* __restrict__ Vp, const float* __restrict__ imp,
    const float* __restrict__ scal, int scal_idx, int kth,
    float* __restrict__ mem_out, int add_to) {
  __shared__ float q_l[4][CHD];
  __shared__ ushort_t sc_l[4][M];
  __shared__ ushort_t il[4][LCAP];
  __shared__ int hist[256];
  __shared__ int hc[256];
  __shared__ float fscr[4];
  __shared__ int iscr[4];
  __shared__ int bsel, ksel;

  int tid = threadIdx.x;
  int idx = blockIdx.x;
  int sg = idx & (CS / 4 - 1);
  int h = (idx >> 7) & (CH - 1);
  int b = idx >> 11;
  int s0 = sg * 4;

  {
    int qi = tid >> 6, d = tid & 63;
    q_l[qi][d] = Q[((size_t)(b * CS + s0 + qi)) * CD + h * CHD + d];
  }
  __syncthreads();

  float lmax0 = -1e30f, lmax1 = -1e30f, lmax2 = -1e30f, lmax3 = -1e30f;
  for (int j0 = 0; j0 < NPT; j0 += 2) {
    int m0 = tid + j0 * 256;
    int m1 = m0 + 256;
    float a00 = 0, a01 = 0, a10 = 0, a11 = 0, a20 = 0, a21 = 0, a30 = 0, a31 = 0;
#pragma unroll
    for (int qt = 0; qt < 4; ++qt) {
      const float4* r0 = (const float4*)(Kp + (size_t)m0 * CD + h * CHD + qt * 16);
      const float4* r1 = (const float4*)(Kp + (size_t)m1 * CD + h * CHD + qt * 16);
      float4 kA[4], kB[4];
#pragma unroll
      for (int c = 0; c < 4; ++c) { kA[c] = r0[c]; kB[c] = r1[c]; }
#pragma unroll
      for (int c = 0; c < 4; ++c) {
        float4 q0 = *(const float4*)&q_l[0][qt * 16 + c * 4];
        float4 q1 = *(const float4*)&q_l[1][qt * 16 + c * 4];
        float4 q2 = *(const float4*)&q_l[2][qt * 16 + c * 4];
        float4 q3 = *(const float4*)&q_l[3][qt * 16 + c * 4];
        a00 += kA[c].x * q0.x + kA[c].y * q0.y + kA[c].z * q0.z + kA[c].w * q0.w;
        a01 += kB[c].x * q0.x + kB[c].y * q0.y + kB[c].z * q0.z + kB[c].w * q0.w;
        a10 += kA[c].x * q1.x + kA[c].y * q1.y + kA[c].z * q1.z + kA[c].w * q1.w;
        a11 += kB[c].x * q1.x + kB[c].y * q1.y + kB[c].z * q1.z + kB[c].w * q1.w;
        a20 += kA[c].x * q2.x + kA[c].y * q2.y + kA[c].z * q2.z + kA[c].w * q2.w;
        a21 += kB[c].x * q2.x + kB[c].y * q2.y + kB[c].z * q2.z + kB[c].w * q2.w;
        a30 += kA[c].x * q3.x + kA[c].y * q3.y + kA[c].z * q3.z + kA[c].w * q3.w;
        a31 += kB[c].x * q3.x + kB[c].y * q3.y + kB[c].z * q3.z + kB[c].w * q3.w;
      }
    }
    float f0 = 0.125f * imp[m0], f1 = 0.125f * imp[m1];
    float s00 = a00 * f0, s01 = a01 * f1;
    float s10 = a10 * f0, s11 = a11 * f1;
    float s20 = a20 * f0, s21 = a21 * f1;
    float s30 = a30 * f0, s31 = a31 * f1;
    sc_l[0][m0] = f2bf(s00); sc_l[0][m1] = f2bf(s01);
    sc_l[1][m0] = f2bf(s10); sc_l[1][m1] = f2bf(s11);
    sc_l[2][m0] = f2bf(s20); sc_l[2][m1] = f2bf(s21);
    sc_l[3][m0] = f2bf(s30); sc_l[3][m1] = f2bf(s31);
    lmax0 = fmaxf(lmax0, fmaxf(s00, s01));
    lmax1 = fmaxf(lmax1, fmaxf(s10, s11));
    lmax2 = fmaxf(lmax2, fmaxf(s20, s21));
    lmax3 = fmaxf(lmax3, fmaxf(s30, s31));
  }

  float gmaxr[4];
  {
    __shared__ float fs2[4];
#pragma unroll
    for (int q = 0; q < 4; ++q) {
      float v = (q == 0) ? lmax0 : (q == 1) ? lmax1 : (q == 2) ? lmax2 : lmax3;
#pragma unroll
      for (int o = 32; o > 0; o >>= 1) v = fmaxf(v, __shfl_down(v, o, 64));
      if ((tid & 63) == 0) fs2[tid >> 6] = v;
      __syncthreads();
      gmaxr[q] = fmaxf(fmaxf(fs2[0], fs2[1]), fmaxf(fs2[2], fs2[3]));
      __syncthreads();
    }
  }

  float wsumr[4];
  int nselr[4];

  for (int qi = 0; qi < 4; ++qi) {
    hist[tid] = 0;
    __syncthreads();
#pragma unroll
    for (int j = 0; j < NPT; ++j) {
      ushort_t u = sc_l[qi][tid + j * 256];
      atomicAdd(&hist[mono16(u) >> 8], 1);
    }
    __syncthreads();
    hc[tid] = hist[tid];
    __syncthreads();
#pragma unroll
    for (int off = 1; off < 256; off <<= 1) {
      int add = (tid + off < 256) ? hc[tid + off] : 0;
      __syncthreads();
      hc[tid] += add;
      __syncthreads();
    }
    if (hc[tid] >= kth && (tid == 255 || hc[tid + 1] < kth)) {
      bsel = tid;
      ksel = kth - (tid == 255 ? 0 : hc[tid + 1]);
    }
    __syncthreads();
    int b1 = bsel, kp = ksel;
    __syncthreads();
    hist[tid] = 0;
    __syncthreads();
#pragma unroll
    for (int j = 0; j < NPT; ++j) {
      int mn = mono16(sc_l[qi][tid + j * 256]);
      if ((mn >> 8) == b1) atomicAdd(&hist[mn & 0xFF], 1);
    }
    __syncthreads();
    hc[tid] = hist[tid];
    __syncthreads();
#pragma unroll
    for (int off = 1; off < 256; off <<= 1) {
      int add = (tid + off < 256) ? hc[tid + off] : 0;
      __syncthreads();
      hc[tid] += add;
      __syncthreads();
    }
    if (hc[tid] >= kp && (tid == 255 || hc[tid + 1] < kp)) bsel = tid;
    __syncthreads();
    int thr = (b1 << 8) | bsel;
    __syncthreads();

    float gm = gmaxr[qi];
    int cnt = 0;
    float ws = 0.f;
#pragma unroll
    for (int j = 0; j < NPT; ++j) {
      ushort_t u = sc_l[qi][tid + j * 256];
      if ((int)mono16(u) >= thr) {
        cnt++;
        ws += __expf(bf2f(u) - gm);
      }
    }
    int lane = tid & 63, wv = tid >> 6;
    int v = cnt;
#pragma unroll
    for (int off = 1; off < 64; off <<= 1) {
      int tt = __shfl_up(v, off, 64);
      if (lane >= off) v += tt;
    }
    if (lane == 63) iscr[wv] = v;
    __syncthreads();
    int base = 0;
#pragma unroll
    for (int ww = 0; ww < 4; ++ww)
      if (ww < wv) base += iscr[ww];
    int pos = base + v - cnt;
    int ntot = iscr[0] + iscr[1] + iscr[2] + iscr[3];
    __syncthreads();
#pragma unroll
    for (int j = 0; j < NPT; ++j) {
      int m = tid + j * 256;
      ushort_t u = sc_l[qi][m];
      if ((int)mono16(u) >= thr) {
        if (pos < LCAP) il[qi][pos] = (ushort_t)m;
        pos++;
      }
    }
    wsumr[qi] = block_sum_f(ws, fscr, tid);
    nselr[qi] = ntot < LCAP ? ntot : LCAP;
    __syncthreads();
  }

  {
    int wv = tid >> 6, d = tid & 63;
    float gm = gmaxr[wv];
    float wsc = scal[scal_idx] / wsumr[wv];
    int n = nselr[wv];
    const float* Vh = Vp + h * CHD + d;
    float acc = 0.f;
    int i = 0;
    for (; i + 4 <= n; i += 4) {
      int m0 = il[wv][i], m1 = il[wv][i + 1], m2 = il[wv][i + 2], m3 = il[wv][i + 3];
      float v0 = Vh[(size_t)m0 * CD];
      float v1 = Vh[(size_t)m1 * CD];
      float v2 = Vh[(size_t)m2 * CD];
      float v3 = Vh[(size_t)m3 * CD];
      float w0 = __expf(bf2f(sc_l[wv][m0]) - gm);
      float w1 = __expf(bf2f(sc_l[wv][m1]) - gm);
      float w2 = __expf(bf2f(sc_l[wv][m2]) - gm);
      float w3 = __expf(bf2f(sc_l[wv][m3]) - gm);
      acc += w0 * v0 + w1 * v1 + w2 * v2 + w3 * v3;
    }
    for (; i < n; ++i) {
      int m0 = il[wv][i];
      acc += __expf(bf2f(sc_l[wv][m0]) - gm) * Vh[(size_t)m0 * CD];
    }
    size_t off = ((size_t)(b * CS + s0 + wv)) * CD + h * CHD + d;
    float o = acc * wsc;
    if (add_to) mem_out[off] += o;
    else mem_out[off] = o;
  }
}

// ---------------- K3: gate + residual + LayerNorm ----------------
__global__ __launch_bounds__(256) void gate_ln_kernel(
    const float* __restrict__ X, const float* __restrict__ Mem,
    const float* __restrict__ Wg, const float* __restrict__ bg,
    const float* __restrict__ lng, const float* __restrict__ lnb,
    float* __restrict__ Out) {
  __shared__ float scr[4];
  int tid = threadIdx.x;
  int row = blockIdx.x;
  int d0 = tid * 4;

  float4 px = *(const float4*)(X + (size_t)row * CD + d0);
  float4 pm = *(const float4*)(Mem + (size_t)row * CD + d0);
  float4 wi = *(const float4*)(Wg + d0);
  float4 wm = *(const float4*)(Wg + CD + d0);

  float t = px.x * wi.x + px.y * wi.y + px.z * wi.z + px.w * wi.w +
            pm.x * wm.x + pm.y * wm.y + pm.z * wm.z + pm.w * wm.w;
  float z = block_sum_f(t, scr, tid) + bg[0];
  float gate = 1.f / (1.f + __expf(-z));

  float xr0 = px.x + pm.x * gate;
  float xr1 = px.y + pm.y * gate;
  float xr2 = px.z + pm.z * gate;
  float xr3 = px.w + pm.w * gate;

  float ssum = block_sum_f(xr0 + xr1 + xr2 + xr3, scr, tid);
  float ssq = block_sum_f(xr0 * xr0 + xr1 * xr1 + xr2 * xr2 + xr3 * xr3, scr, tid);
  float mu = ssum * (1.f / CD);
  float var = ssq * (1.f / CD) - mu * mu;
  float inv = rsqrtf(var + 1e-5f);

  float4 pg = *(const float4*)(lng + d0);
  float4 pb = *(const float4*)(lnb + d0);
  float4 o;
  o.x = (xr0 - mu) * inv * pg.x + pb.x;
  o.y = (xr1 - mu) * inv * pg.y + pb.y;
  o.z = (xr2 - mu) * inv * pg.z + pb.z;
  o.w = (xr3 - mu) * inv * pg.w + pb.w;
  *(float4*)(Out + (size_t)row * CD + d0) = o;
}

extern "C" void kernel_launch(void* const* d_in, const int* in_sizes, int n_in,
                              void* d_out, int out_size, void* d_ws, size_t ws_size,
                              hipStream_t stream) {
  const float* inputs = (const float*)d_in[0];
  const float* Wq = (const float*)d_in[1];
  const float* bq = (const float*)d_in[2];
  const float* st_keys = (const float*)d_in[3];
  const float* st_values = (const float*)d_in[4];
  const float* lt_keys = (const float*)d_in[5];
  const float* lt_values = (const float*)d_in[6];
  const float* st_imp = (const float*)d_in[7];
  const float* lt_imp = (const float*)d_in[8];
  const float* Wg = (const float*)d_in[9];
  const float* bg = (const float*)d_in[10];
  const float* ln_g = (const float*)d_in[11];
  const float* ln_b = (const float*)d_in[12];
  float* out = (float*)d_out;

  size_t nQ = (size_t)CB * CS * CD;
  float* Qws = (float*)d_ws;
  float* Memws = Qws + nQ;
  float* scal = Memws + nQ;
  ushort_t* KTst = (ushort_t*)(scal + 64);
  ushort_t* KTlt = KTst + (size_t)CD * CST;
  size_t need = (size_t)((char*)(KTlt + (size_t)CD * CLT) - (char*)d_ws);

  int nblk = CB * CH * (CS / 4);  // 4096

  prep_kernel<<<1, 256, 0, stream>>>(st_imp, lt_imp, scal);
  qproj_kernel<<<CB * CS / 4, 256, 0, stream>>>(inputs, Wq, bq, Qws);

  if (ws_size >= need) {
    ktrans_kernel<CST><<<(CST / 64) * CH, 256, 0, stream>>>(st_keys, KTst);
    ktrans_kernel<CLT><<<(CLT / 64) * CH, 256, 0, stream>>>(lt_keys, KTlt);
    attn_v6<CST, 512><<<nblk, 512, 0, stream>>>(
        Qws, KTst, st_values, st_imp, scal, 0, CKST, Memws, 0);
    attn_v6<CLT, 1024><<<nblk, 512, 0, stream>>>(
        Qws, KTlt, lt_values, lt_imp, scal, 1, CKLT, Memws, 1);
  } else {
    attn_v2<CST, CST / 256, 512><<<nblk, 256, 0, stream>>>(
        Qws, st_keys, st_values, st_imp, scal, 0, CKST, Memws, 0);
    attn_v2<CLT, CLT / 256, 1024><<<nblk, 256, 0, stream>>>(
        Qws, lt_keys, lt_values, lt_imp, scal, 1, CKLT, Memws, 1);
  }
  gate_ln_kernel<<<CB * CS, 256, 0, stream>>>(inputs, Memws, Wg, bg, ln_g, ln_b, out);
}

// Round 10
// 1134.274 us; speedup vs baseline: 1.2809x; 1.0849x over previous
//
#include <hip/hip_runtime.h>
#include <hip/hip_bf16.h>

typedef unsigned short ushort_t;
typedef __attribute__((ext_vector_type(8))) short bf16x8;
typedef __attribute__((ext_vector_type(4))) float f32x4;

constexpr int CB = 2, CS = 512, CD = 1024, CH = 16, CHD = 64;
constexpr int CST = 2048, CLT = 6144;
constexpr int CKST = 204, CKLT = 614;

__device__ __forceinline__ float u2f(unsigned u) { return __uint_as_float(u); }
__device__ __forceinline__ float bf2f(ushort_t u) {
  return __uint_as_float(((unsigned)u) << 16);
}
__device__ __forceinline__ ushort_t f2bf(float f) {
  __hip_bfloat16 h = __float2bfloat16(f);
  return *reinterpret_cast<ushort_t*>(&h);
}
// monotone 16-bit key: mono(a) > mono(b) <=> bf16 a > b
__device__ __forceinline__ unsigned mono16(ushort_t u) {
  return (u & 0x8000) ? (unsigned)((ushort_t)~u) : (unsigned)(u | 0x8000);
}

__device__ __forceinline__ float block_sum_f(float v, float* scratch, int tid) {
#pragma unroll
  for (int o = 32; o > 0; o >>= 1) v += __shfl_down(v, o, 64);
  if ((tid & 63) == 0) scratch[tid >> 6] = v;
  __syncthreads();
  float r = (scratch[0] + scratch[1]) + (scratch[2] + scratch[3]);
  __syncthreads();
  return r;
}

// ---------------- K0: bank-mix coefficients ----------------
__global__ __launch_bounds__(256) void prep_kernel(
    const float* __restrict__ st_imp, const float* __restrict__ lt_imp,
    float* __restrict__ scal) {
  __shared__ float scr[4];
  int tid = threadIdx.x;
  float s = 0.f, l = 0.f;
  for (int i = tid; i < CST; i += 256) s += st_imp[i];
  for (int i = tid; i < CLT; i += 256) l += lt_imp[i];
  float ssum = block_sum_f(s, scr, tid);
  float lsum = block_sum_f(l, scr, tid);
  if (tid == 0) {
    float sw = 1.f / (1.f + __expf(-(ssum / CST)));
    float lw = 1.f / (1.f + __expf(-(lsum / CLT)));
    float tot = sw + lw;
    scal[0] = sw / tot;
    scal[1] = lw / tot;
  }
}

// ---------------- K1: Q = X @ Wq + bq ----------------
__global__ __launch_bounds__(256) void qproj_kernel(
    const float* __restrict__ X, const float* __restrict__ Wq,
    const float* __restrict__ bq, float* __restrict__ Qout) {
  __shared__ float xs[4][CD];
  int tid = threadIdx.x;
  int row0 = blockIdx.x * 4;
#pragma unroll
  for (int r = 0; r < 4; ++r)
    for (int dd = tid; dd < CD; dd += 256)
      xs[r][dd] = X[(size_t)(row0 + r) * CD + dd];
  __syncthreads();

  float acc[4][4];
#pragma unroll
  for (int r = 0; r < 4; ++r)
#pragma unroll
    for (int j = 0; j < 4; ++j) acc[r][j] = 0.f;

  int j0 = tid * 4;
  for (int dd = 0; dd < CD; dd += 2) {
    float4 w0 = *(const float4*)&Wq[(size_t)dd * CD + j0];
    float4 w1 = *(const float4*)&Wq[(size_t)(dd + 1) * CD + j0];
#pragma unroll
    for (int r = 0; r < 4; ++r) {
      float x0 = xs[r][dd], x1 = xs[r][dd + 1];
      acc[r][0] += x0 * w0.x + x1 * w1.x;
      acc[r][1] += x0 * w0.y + x1 * w1.y;
      acc[r][2] += x0 * w0.z + x1 * w1.z;
      acc[r][3] += x0 * w0.w + x1 * w1.w;
    }
  }
  float4 bb = *(const float4*)&bq[j0];
#pragma unroll
  for (int r = 0; r < 4; ++r) {
    float4 o;
    o.x = acc[r][0] + bb.x;
    o.y = acc[r][1] + bb.y;
    o.z = acc[r][2] + bb.z;
    o.w = acc[r][3] + bb.w;
    *(float4*)&Qout[(size_t)(row0 + r) * CD + j0] = o;
  }
}

// ---------------- K-repack: K[m][h*64+d] f32 -> KH[h][m][64] bf16 -------------
template <int M>
__global__ __launch_bounds__(256) void krepack_kernel(
    const float* __restrict__ K, ushort_t* __restrict__ KH) {
  int m = blockIdx.x * 4 + (threadIdx.x >> 6);
  int d = threadIdx.x & 63;
  const float* src = K + (size_t)m * CD;
#pragma unroll
  for (int h = 0; h < CH; ++h) {
    KH[((size_t)h * M + m) * 64 + d] = f2bf(src[h * CHD + d]);
  }
}

// ---------------- K2 v7: MFMA phase 1 + v6 select/PV -------------------------
// 512 threads (8 waves), 4 queries/block. Phase 1 per wave: M/8 key strip in
// 16-key tiles via mfma_f32_16x16x32_bf16 (A = K-tile 16x32, B = Q with 4 real
// cols + 12 zero). D: col(lane&15)=query, row((lane>>4)*4+reg)=key. Epilogue
// (16 active lanes) scales by 0.125*imp, packs bf16 into sc_l.
// Select/compaction/w-fill/PV identical to v6 (reg-resident binary search).
template <int M, int LCAP>
__global__ __launch_bounds__(512, 4) void attn_v7(
    const float* __restrict__ Q, const ushort_t* __restrict__ KH,
    const float* __restrict__ Vp, const float* __restrict__ imp,
    const float* __restrict__ scal, int scal_idx, int kth,
    float* __restrict__ mem_out, int add_to) {
  constexpr int NJ = M / 512;   // uint2 per lane covering this wave's half
  constexpr int HC = LCAP / 2;  // per-half list capacity
  constexpr int MP = M + 8;     // padded row to de-alias query-row banks

  __shared__ ushort_t sc_l[4][MP];
  __shared__ ushort_t il[4][2][HC];
  __shared__ float q_l[4][CHD];
  __shared__ float wmax[8][4];
  __shared__ int cntw[2][4][2];
  __shared__ float wsp[4][2];
  __shared__ float pacc[4][2][CHD];

  int tid = threadIdx.x;
  int l = tid & 63;
  int w = tid >> 6;        // 0..7
  int wq = w & 3;          // query this wave serves in select/PV
  int half = w >> 2;       // 0/1: which half of M
  int idx = blockIdx.x;
  int sg = idx & (CS / 4 - 1);
  int h = (idx >> 7) & (CH - 1);
  int b = idx >> 11;
  int s0 = sg * 4;
  int h6 = h * CHD;

  if (tid < 256)
    q_l[tid >> 6][tid & 63] = Q[((size_t)(b * CS + s0 + (tid >> 6))) * CD + h6 + (tid & 63)];
  __syncthreads();

  // ---- build Q B-fragments (loop-invariant). col = lane&15 (query slot),
  //      k = (lane>>4)*8 + j. Only cols 0..3 are real queries.
  int col = l & 15;
  int kbase = (l >> 4) * 8;
  bf16x8 bq0, bq1;
#pragma unroll
  for (int j = 0; j < 8; ++j) { bq0[j] = 0; bq1[j] = 0; }
  if (col < 4) {
#pragma unroll
    for (int j = 0; j < 8; ++j) {
      bq0[j] = (short)f2bf(q_l[col][kbase + j]);
      bq1[j] = (short)f2bf(q_l[col][32 + kbase + j]);
    }
  }

  // ---- phase 1: MFMA scores over strip [w*M/8, (w+1)*M/8), 16-key tiles ----
  float lmax_q = -1e30f;  // per-lane: max over this lane's query (col), if col<4
  const ushort_t* KHh = KH + (size_t)h * M * 64;
#pragma unroll 1
  for (int tile = 0; tile < M / 128; ++tile) {
    int m0 = w * (M / 8) + tile * 16;
    const ushort_t* ka = KHh + (size_t)(m0 + col) * 64 + kbase;
    bf16x8 a0 = *(const bf16x8*)ka;         // dims 0..31 slice
    bf16x8 a1 = *(const bf16x8*)(ka + 32);  // dims 32..63 slice
    f32x4 dfrag = {0.f, 0.f, 0.f, 0.f};
    dfrag = __builtin_amdgcn_mfma_f32_16x16x32_bf16(a0, bq0, dfrag, 0, 0, 0);
    dfrag = __builtin_amdgcn_mfma_f32_16x16x32_bf16(a1, bq1, dfrag, 0, 0, 0);
    if (col < 4) {
      int mb = m0 + (l >> 4) * 4;
      float4 ip = *(const float4*)&imp[mb];
      float s0v = dfrag[0] * 0.125f * ip.x;
      float s1v = dfrag[1] * 0.125f * ip.y;
      float s2v = dfrag[2] * 0.125f * ip.z;
      float s3v = dfrag[3] * 0.125f * ip.w;
      lmax_q = fmaxf(lmax_q, fmaxf(fmaxf(s0v, s1v), fmaxf(s2v, s3v)));
      unsigned p0 = (unsigned)f2bf(s0v) | ((unsigned)f2bf(s1v) << 16);
      unsigned p1 = (unsigned)f2bf(s2v) | ((unsigned)f2bf(s3v) << 16);
      *(uint2*)&sc_l[col][mb] = make_uint2(p0, p1);
    }
  }
  // wave max per query: lanes {q, q+16, q+32, q+48} hold partials for query q
  lmax_q = fmaxf(lmax_q, __shfl_xor(lmax_q, 16, 64));
  lmax_q = fmaxf(lmax_q, __shfl_xor(lmax_q, 32, 64));
  if (l < 4) wmax[w][l] = lmax_q;
  __syncthreads();

  // global max for this wave's query
  float t = wmax[0][wq];
#pragma unroll
  for (int ww = 1; ww < 8; ++ww) t = fmaxf(t, wmax[ww][wq]);

  // ---- load this half's scores once; keep mono16 keys in registers ----
  int ms = half * (M / 2);
  unsigned mreg[2 * NJ];
#pragma unroll
  for (int j = 0; j < NJ; ++j) {
    uint2 sv = *(const uint2*)&sc_l[wq][ms + j * 256 + 4 * l];
    mreg[2 * j] = mono16((ushort_t)(sv.x & 0xFFFF)) |
                  (mono16((ushort_t)(sv.x >> 16)) << 16);
    mreg[2 * j + 1] = mono16((ushort_t)(sv.y & 0xFFFF)) |
                      (mono16((ushort_t)(sv.y >> 16)) << 16);
  }

  // ---- 16-iter binary search for k-th-largest threshold (no atomics) ----
  unsigned lo = 0u, hi = 0xFFFFu;
#pragma unroll 1
  for (int it = 0; it < 16; ++it) {
    unsigned mid = lo + ((hi - lo + 1u) >> 1);
    int cnt = 0;
#pragma unroll
    for (int j = 0; j < 2 * NJ; ++j) {
      cnt += (int)((mreg[j] & 0xFFFFu) >= mid);
      cnt += (int)((mreg[j] >> 16) >= mid);
    }
#pragma unroll
    for (int off = 32; off > 0; off >>= 1) cnt += __shfl_down(cnt, off, 64);
    if (l == 0) cntw[it & 1][wq][half] = cnt;
    __syncthreads();
    int tot = cntw[it & 1][wq][0] + cntw[it & 1][wq][1];
    if (tot >= kth) lo = mid;
    else hi = mid - 1u;
  }
  unsigned thr = lo;

  // ---- single ballot compaction pass (from registers) ----
  unsigned long long lt_mask = (1ull << l) - 1ull;
  int pos = 0;
#pragma unroll
  for (int j = 0; j < NJ; ++j) {
#pragma unroll
    for (int e = 0; e < 4; ++e) {
      unsigned mv = (mreg[2 * j + (e >> 1)] >> ((e & 1) * 16)) & 0xFFFFu;
      bool sel = mv >= thr;
      unsigned long long mask = __ballot(sel);
      if (sel) {
        int p = pos + __builtin_popcountll(mask & lt_mask);
        if (p < HC) il[wq][half][p] = (ushort_t)(ms + j * 256 + 4 * l + e);
      }
      pos += __builtin_popcountll(mask);
    }
  }
  int nhalf = pos < HC ? pos : HC;

  // ---- w-fill: exp once per selected row; overwrite sc_l with bf16 w ----
  float wsum = 0.f;
  for (int i = l; i < nhalf; i += 64) {
    int m = il[wq][half][i];
    float wv = __expf(bf2f(sc_l[wq][m]) - t);
    wsum += wv;
    sc_l[wq][m] = f2bf(wv);
  }
#pragma unroll
  for (int off = 32; off > 0; off >>= 1) wsum += __shfl_down(wsum, off, 64);
  if (l == 0) wsp[wq][half] = wsum;

  // ---- PV over this half's selected rows ----
  {
    const float* Vb = Vp + h6;  // uniform base; per-lane 32-bit element index
    float acc3 = 0.f;
    int i = 0;
    for (; i + 4 <= nhalf; i += 4) {
      uint2 pk = *(const uint2*)&il[wq][half][i];
      int m0 = pk.x & 0xFFFF, m1 = pk.x >> 16;
      int m2 = pk.y & 0xFFFF, m3 = pk.y >> 16;
      float w0 = bf2f(sc_l[wq][m0]);
      float w1 = bf2f(sc_l[wq][m1]);
      float w2 = bf2f(sc_l[wq][m2]);
      float w3 = bf2f(sc_l[wq][m3]);
      float v0 = Vb[(unsigned)(m0 << 10) + l];
      float v1 = Vb[(unsigned)(m1 << 10) + l];
      float v2 = Vb[(unsigned)(m2 << 10) + l];
      float v3 = Vb[(unsigned)(m3 << 10) + l];
      acc3 += w0 * v0 + w1 * v1 + w2 * v2 + w3 * v3;
    }
    for (; i < nhalf; ++i) {
      int m0 = il[wq][half][i];
      acc3 += bf2f(sc_l[wq][m0]) * Vb[(unsigned)(m0 << 10) + l];
    }
    pacc[wq][half][l] = acc3;
  }
  __syncthreads();
  if (half == 0) {
    float o = (pacc[wq][0][l] + pacc[wq][1][l]) *
              (scal[scal_idx] / (wsp[wq][0] + wsp[wq][1]));
    size_t off = ((size_t)(b * CS + s0 + wq)) * CD + h6 + l;
    if (add_to) mem_out[off] += o;
    else mem_out[off] = o;
  }
}

// ---------------- K2 v2 (fallback if ws too small) ----------
template <int M, int NPT, int LCAP>
__global__ __launch_bounds__(256) void attn_v2(
    const float* __restrict__ Q, const float* __restrict__ Kp,
    const float* __restrict__ Vp, const float* __restrict__ imp,
    const float* __restrict__ scal, int scal_idx, int kth,
    float* __restrict__ mem_out, int add_to) {
  __shared__ float q_l[4][CHD];
  __shared__ ushort_t sc_l[4][M];
  __shared__ ushort_t il[4][LCAP];
  __shared__ int hist[256];
  __shared__ int hc[256];
  __shared__ float fscr[4];
  __shared__ int iscr[4];
  __shared__ int bsel, ksel;

  int tid = threadIdx.x;
  int idx = blockIdx.x;
  int sg = idx & (CS / 4 - 1);
  int h = (idx >> 7) & (CH - 1);
  int b = idx >> 11;
  int s0 = sg * 4;

  {
    int qi = tid >> 6, d = tid & 63;
    q_l[qi][d] = Q[((size_t)(b * CS + s0 + qi)) * CD + h * CHD + d];
  }
  __syncthreads();

  float lmax0 = -1e30f, lmax1 = -1e30f, lmax2 = -1e30f, lmax3 = -1e30f;
  for (int j0 = 0; j0 < NPT; j0 += 2) {
    int m0 = tid + j0 * 256;
    int m1 = m0 + 256;
    float a00 = 0, a01 = 0, a10 = 0, a11 = 0, a20 = 0, a21 = 0, a30 = 0, a31 = 0;
#pragma unroll
    for (int qt = 0; qt < 4; ++qt) {
      const float4* r0 = (const float4*)(Kp + (size_t)m0 * CD + h * CHD + qt * 16);
      const float4* r1 = (const float4*)(Kp + (size_t)m1 * CD + h * CHD + qt * 16);
      float4 kA[4], kB[4];
#pragma unroll
      for (int c = 0; c < 4; ++c) { kA[c] = r0[c]; kB[c] = r1[c]; }
#pragma unroll
      for (int c = 0; c < 4; ++c) {
        float4 q0 = *(const float4*)&q_l[0][qt * 16 + c * 4];
        float4 q1 = *(const float4*)&q_l[1][qt * 16 + c * 4];
        float4 q2 = *(const float4*)&q_l[2][qt * 16 + c * 4];
        float4 q3 = *(const float4*)&q_l[3][qt * 16 + c * 4];
        a00 += kA[c].x * q0.x + kA[c].y * q0.y + kA[c].z * q0.z + kA[c].w * q0.w;
        a01 += kB[c].x * q0.x + kB[c].y * q0.y + kB[c].z * q0.z + kB[c].w * q0.w;
        a10 += kA[c].x * q1.x + kA[c].y * q1.y + kA[c].z * q1.z + kA[c].w * q1.w;
        a11 += kB[c].x * q1.x + kB[c].y * q1.y + kB[c].z * q1.z + kB[c].w * q1.w;
        a20 += kA[c].x * q2.x + kA[c].y * q2.y + kA[c].z * q2.z + kA[c].w * q2.w;
        a21 += kB[c].x * q2.x + kB[c].y * q2.y + kB[c].z * q2.z + kB[c].w * q2.w;
        a30 += kA[c].x * q3.x + kA[c].y * q3.y + kA[c].z * q3.z + kA[c].w * q3.w;
        a31 += kB[c].x * q3.x + kB[c].y * q3.y + kB[c].z * q3.z + kB[c].w * q3.w;
      }
    }
    float f0 = 0.125f * imp[m0], f1 = 0.125f * imp[m1];
    float s00 = a00 * f0, s01 = a01 * f1;
    float s10 = a10 * f0, s11 = a11 * f1;
    float s20 = a20 * f0, s21 = a21 * f1;
    float s30 = a30 * f0, s31 = a31 * f1;
    sc_l[0][m0] = f2bf(s00); sc_l[0][m1] = f2bf(s01);
    sc_l[1][m0] = f2bf(s10); sc_l[1][m1] = f2bf(s11);
    sc_l[2][m0] = f2bf(s20); sc_l[2][m1] = f2bf(s21);
    sc_l[3][m0] = f2bf(s30); sc_l[3][m1] = f2bf(s31);
    lmax0 = fmaxf(lmax0, fmaxf(s00, s01));
    lmax1 = fmaxf(lmax1, fmaxf(s10, s11));
    lmax2 = fmaxf(lmax2, fmaxf(s20, s21));
    lmax3 = fmaxf(lmax3, fmaxf(s30, s31));
  }

  float gmaxr[4];
  {
    __shared__ float fs2[4];
#pragma unroll
    for (int q = 0; q < 4; ++q) {
      float v = (q == 0) ? lmax0 : (q == 1) ? lmax1 : (q == 2) ? lmax2 : lmax3;
#pragma unroll
      for (int o = 32; o > 0; o >>= 1) v = fmaxf(v, __shfl_down(v, o, 64));
      if ((tid & 63) == 0) fs2[tid >> 6] = v;
      __syncthreads();
      gmaxr[q] = fmaxf(fmaxf(fs2[0], fs2[1]), fmaxf(fs2[2], fs2[3]));
      __syncthreads();
    }
  }

  float wsumr[4];
  int nselr[4];

  for (int qi = 0; qi < 4; ++qi) {
    hist[tid] = 0;
    __syncthreads();
#pragma unroll
    for (int j = 0; j < NPT; ++j) {
      ushort_t u = sc_l[qi][tid + j * 256];
      atomicAdd(&hist[mono16(u) >> 8], 1);
    }
    __syncthreads();
    hc[tid] = hist[tid];
    __syncthreads();
#pragma unroll
    for (int off = 1; off < 256; off <<= 1) {
      int add = (tid + off < 256) ? hc[tid + off] : 0;
      __syncthreads();
      hc[tid] += add;
      __syncthreads();
    }
    if (hc[tid] >= kth && (tid == 255 || hc[tid + 1] < kth)) {
      bsel = tid;
      ksel = kth - (tid == 255 ? 0 : hc[tid + 1]);
    }
    __syncthreads();
    int b1 = bsel, kp = ksel;
    __syncthreads();
    hist[tid] = 0;
    __syncthreads();
#pragma unroll
    for (int j = 0; j < NPT; ++j) {
      int mn = mono16(sc_l[qi][tid + j * 256]);
      if ((mn >> 8) == b1) atomicAdd(&hist[mn & 0xFF], 1);
    }
    __syncthreads();
    hc[tid] = hist[tid];
    __syncthreads();
#pragma unroll
    for (int off = 1; off < 256; off <<= 1) {
      int add = (tid + off < 256) ? hc[tid + off] : 0;
      __syncthreads();
      hc[tid] += add;
      __syncthreads();
    }
    if (hc[tid] >= kp && (tid == 255 || hc[tid + 1] < kp)) bsel = tid;
    __syncthreads();
    int thr = (b1 << 8) | bsel;
    __syncthreads();

    float gm = gmaxr[qi];
    int cnt = 0;
    float ws = 0.f;
#pragma unroll
    for (int j = 0; j < NPT; ++j) {
      ushort_t u = sc_l[qi][tid + j * 256];
      if ((int)mono16(u) >= thr) {
        cnt++;
        ws += __expf(bf2f(u) - gm);
      }
    }
    int lane = tid & 63, wv = tid >> 6;
    int v = cnt;
#pragma unroll
    for (int off = 1; off < 64; off <<= 1) {
      int tt = __shfl_up(v, off, 64);
      if (lane >= off) v += tt;
    }
    if (lane == 63) iscr[wv] = v;
    __syncthreads();
    int base = 0;
#pragma unroll
    for (int ww = 0; ww < 4; ++ww)
      if (ww < wv) base += iscr[ww];
    int pos = base + v - cnt;
    int ntot = iscr[0] + iscr[1] + iscr[2] + iscr[3];
    __syncthreads();
#pragma unroll
    for (int j = 0; j < NPT; ++j) {
      int m = tid + j * 256;
      ushort_t u = sc_l[qi][m];
      if ((int)mono16(u) >= thr) {
        if (pos < LCAP) il[qi][pos] = (ushort_t)m;
        pos++;
      }
    }
    wsumr[qi] = block_sum_f(ws, fscr, tid);
    nselr[qi] = ntot < LCAP ? ntot : LCAP;
    __syncthreads();
  }

  {
    int wv = tid >> 6, d = tid & 63;
    float gm = gmaxr[wv];
    float wsc = scal[scal_idx] / wsumr[wv];
    int n = nselr[wv];
    const float* Vh = Vp + h * CHD + d;
    float acc = 0.f;
    int i = 0;
    for (; i + 4 <= n; i += 4) {
      int m0 = il[wv][i], m1 = il[wv][i + 1], m2 = il[wv][i + 2], m3 = il[wv][i + 3];
      float v0 = Vh[(size_t)m0 * CD];
      float v1 = Vh[(size_t)m1 * CD];
      float v2 = Vh[(size_t)m2 * CD];
      float v3 = Vh[(size_t)m3 * CD];
      float w0 = __expf(bf2f(sc_l[wv][m0]) - gm);
      float w1 = __expf(bf2f(sc_l[wv][m1]) - gm);
      float w2 = __expf(bf2f(sc_l[wv][m2]) - gm);
      float w3 = __expf(bf2f(sc_l[wv][m3]) - gm);
      acc += w0 * v0 + w1 * v1 + w2 * v2 + w3 * v3;
    }
    for (; i < n; ++i) {
      int m0 = il[wv][i];
      acc += __expf(bf2f(sc_l[wv][m0]) - gm) * Vh[(size_t)m0 * CD];
    }
    size_t off = ((size_t)(b * CS + s0 + wv)) * CD + h * CHD + d;
    float o = acc * wsc;
    if (add_to) mem_out[off] += o;
    else mem_out[off] = o;
  }
}

// ---------------- K3: gate + residual + LayerNorm ----------------
__global__ __launch_bounds__(256) void gate_ln_kernel(
    const float* __restrict__ X, const float* __restrict__ Mem,
    const float* __restrict__ Wg, const float* __restrict__ bg,
    const float* __restrict__ lng, const float* __restrict__ lnb,
    float* __restrict__ Out) {
  __shared__ float scr[4];
  int tid = threadIdx.x;
  int row = blockIdx.x;
  int d0 = tid * 4;

  float4 px = *(const float4*)(X + (size_t)row * CD + d0);
  float4 pm = *(const float4*)(Mem + (size_t)row * CD + d0);
  float4 wi = *(const float4*)(Wg + d0);
  float4 wm = *(const float4*)(Wg + CD + d0);

  float t = px.x * wi.x + px.y * wi.y + px.z * wi.z + px.w * wi.w +
            pm.x * wm.x + pm.y * wm.y + pm.z * wm.z + pm.w * wm.w;
  float z = block_sum_f(t, scr, tid) + bg[0];
  float gate = 1.f / (1.f + __expf(-z));

  float xr0 = px.x + pm.x * gate;
  float xr1 = px.y + pm.y * gate;
  float xr2 = px.z + pm.z * gate;
  float xr3 = px.w + pm.w * gate;

  float ssum = block_sum_f(xr0 + xr1 + xr2 + xr3, scr, tid);
  float ssq = block_sum_f(xr0 * xr0 + xr1 * xr1 + xr2 * xr2 + xr3 * xr3, scr, tid);
  float mu = ssum * (1.f / CD);
  float var = ssq * (1.f / CD) - mu * mu;
  float inv = rsqrtf(var + 1e-5f);

  float4 pg = *(const float4*)(lng + d0);
  float4 pb = *(const float4*)(lnb + d0);
  float4 o;
  o.x = (xr0 - mu) * inv * pg.x + pb.x;
  o.y = (xr1 - mu) * inv * pg.y + pb.y;
  o.z = (xr2 - mu) * inv * pg.z + pb.z;
  o.w = (xr3 - mu) * inv * pg.w + pb.w;
  *(float4*)(Out + (size_t)row * CD + d0) = o;
}

extern "C" void kernel_launch(void* const* d_in, const int* in_sizes, int n_in,
                              void* d_out, int out_size, void* d_ws, size_t ws_size,
                              hipStream_t stream) {
  const float* inputs = (const float*)d_in[0];
  const float* Wq = (const float*)d_in[1];
  const float* bq = (const float*)d_in[2];
  const float* st_keys = (const float*)d_in[3];
  const float* st_values = (const float*)d_in[4];
  const float* lt_keys = (const float*)d_in[5];
  const float* lt_values = (const float*)d_in[6];
  const float* st_imp = (const float*)d_in[7];
  const float* lt_imp = (const float*)d_in[8];
  const float* Wg = (const float*)d_in[9];
  const float* bg = (const float*)d_in[10];
  const float* ln_g = (const float*)d_in[11];
  const float* ln_b = (const float*)d_in[12];
  float* out = (float*)d_out;

  size_t nQ = (size_t)CB * CS * CD;
  float* Qws = (float*)d_ws;
  float* Memws = Qws + nQ;
  float* scal = Memws + nQ;
  ushort_t* KHst = (ushort_t*)(scal + 64);
  ushort_t* KHlt = KHst + (size_t)CD * CST;
  size_t need = (size_t)((char*)(KHlt + (size_t)CD * CLT) - (char*)d_ws);

  int nblk = CB * CH * (CS / 4);  // 4096

  prep_kernel<<<1, 256, 0, stream>>>(st_imp, lt_imp, scal);
  qproj_kernel<<<CB * CS / 4, 256, 0, stream>>>(inputs, Wq, bq, Qws);

  if (ws_size >= need) {
    krepack_kernel<CST><<<CST / 4, 256, 0, stream>>>(st_keys, KHst);
    krepack_kernel<CLT><<<CLT / 4, 256, 0, stream>>>(lt_keys, KHlt);
    attn_v7<CST, 512><<<nblk, 512, 0, stream>>>(
        Qws, KHst, st_values, st_imp, scal, 0, CKST, Memws, 0);
    attn_v7<CLT, 1024><<<nblk, 512, 0, stream>>>(
        Qws, KHlt, lt_values, lt_imp, scal, 1, CKLT, Memws, 1);
  } else {
    attn_v2<CST, CST / 256, 512><<<nblk, 256, 0, stream>>>(
        Qws, st_keys, st_values, st_imp, scal, 0, CKST, Memws, 0);
    attn_v2<CLT, CLT / 256, 1024><<<nblk, 256, 0, stream>>>(
        Qws, lt_keys, lt_values, lt_imp, scal, 1, CKLT, Memws, 1);
  }
  gate_ln_kernel<<<CB * CS, 256, 0, stream>>>(inputs, Memws, Wg, bg, ln_g, ln_b, out);
}